// Round 5
// baseline (311.407 us; speedup 1.0000x reference)
//
#include <hip/hip_runtime.h>
#include <cstdint>
#include <cstddef>

#define BB   32
#define NN   1024
#define FIN  128
#define FOUT 128

typedef __attribute__((ext_vector_type(8))) short bf16x8;
typedef __attribute__((ext_vector_type(4))) float f32x4;

__device__ __forceinline__ unsigned int f2bf(float f) {
    union { float f; unsigned int u; } v; v.f = f;
    unsigned int u = v.u;
    return (u + 0x7FFFu + ((u >> 16) & 1u)) >> 16;   // RNE fp32 -> bf16
}
__device__ __forceinline__ unsigned int pack2(float a, float b) {
    return f2bf(a) | (f2bf(b) << 16);
}

// async global -> LDS DMA, 16 B/lane; dst is wave-uniform base, HW scatters
// lane i to dst + i*16 (m97/m104 semantics)
__device__ __forceinline__ void load_lds16(const void* g, void* l) {
    __builtin_amdgcn_global_load_lds(
        (const __attribute__((address_space(1))) unsigned int*)g,
        (__attribute__((address_space(3))) unsigned int*)l, 16, 0, 0);
}

// ---------------------------------------------------------------------------
// Kernel 1: Yt[b][o][m] = sum_f node[b][m][f] * W[o][f]  (bf16, [B][FOUT][NN])
// grid 512 = 32 b x 16 m-tiles(64); block 256. LDS-staged. (control, ~10 us)
// ---------------------------------------------------------------------------
__global__ __launch_bounds__(256) void y_kernel(const float* __restrict__ node,
                                                const float* __restrict__ W,
                                                unsigned short* __restrict__ Yt) {
    __shared__ unsigned short Wlds[128 * 136];
    __shared__ unsigned short Nlds[64 * 136];

    const int tid = threadIdx.x;
    const int bid = blockIdx.x;
    const int b   = bid >> 4;
    const int m0  = (bid & 15) * 64;

    #pragma unroll
    for (int i = 0; i < 16; ++i) {
        const int idx = i * 256 + tid;
        const int row = idx >> 5;
        const int c   = (idx & 31) * 4;
        float4 v = ((const float4*)W)[idx];
        uint2 p; p.x = pack2(v.x, v.y); p.y = pack2(v.z, v.w);
        *(uint2*)&Wlds[row * 136 + c] = p;
    }
    {
        const float* base = node + ((size_t)b * NN + m0) * FIN;
        #pragma unroll
        for (int i = 0; i < 8; ++i) {
            const int idx = i * 256 + tid;
            const int row = idx >> 5;
            const int c   = (idx & 31) * 4;
            float4 v = *(const float4*)(base + row * FIN + c);
            uint2 p; p.x = pack2(v.x, v.y); p.y = pack2(v.z, v.w);
            *(uint2*)&Nlds[row * 136 + c] = p;
        }
    }
    __syncthreads();

    const int w = tid >> 6, lane = tid & 63;
    const int wo = w * 32;
    const int lcol = lane & 15, lk = (lane >> 4) * 8;

    f32x4 acc[2][4] = {};
    #pragma unroll
    for (int kc = 0; kc < 4; ++kc) {
        const int kof = kc * 32 + lk;
        bf16x8 a[2], bb[4];
        #pragma unroll
        for (int mi = 0; mi < 2; ++mi)
            a[mi] = *(const bf16x8*)&Wlds[(wo + mi*16 + lcol) * 136 + kof];
        #pragma unroll
        for (int ni = 0; ni < 4; ++ni)
            bb[ni] = *(const bf16x8*)&Nlds[(ni*16 + lcol) * 136 + kof];
        #pragma unroll
        for (int mi = 0; mi < 2; ++mi)
            #pragma unroll
            for (int ni = 0; ni < 4; ++ni)
                acc[mi][ni] = __builtin_amdgcn_mfma_f32_16x16x32_bf16(
                    a[mi], bb[ni], acc[mi][ni], 0, 0, 0);
    }
    __syncthreads();

    unsigned short* Ylds = Wlds;
    const int rq = (lane >> 4) * 4;
    #pragma unroll
    for (int mi = 0; mi < 2; ++mi)
        #pragma unroll
        for (int ni = 0; ni < 4; ++ni)
            #pragma unroll
            for (int r = 0; r < 4; ++r) {
                const int o = wo + mi * 16 + rq + r;
                const int m = ni * 16 + lcol;
                Ylds[o * 72 + m] = (unsigned short)f2bf(acc[mi][ni][r]);
            }
    __syncthreads();

    {
        const int oq = tid >> 3, c = (tid & 7) * 8;
        #pragma unroll
        for (int j = 0; j < 4; ++j) {
            const int o = oq + 32 * j;
            uint4 v = *(const uint4*)&Ylds[o * 72 + c];
            *(uint4*)(Yt + ((size_t)b * FOUT + o) * NN + m0 + c) = v;
        }
    }
}

// ---------------------------------------------------------------------------
// Kernel 2: out = leaky( (adj @ Yt^T) / rowsum(adj) + bias )
// m97-style DMA loop tuned for concurrent barrier drains:
//   grid 2048 = 32 b x 64 n-tiles(16)  -> 8 blocks/CU, 32 waves/CU (full occ)
//   LDS 10 KB: A [8 chunks][16 rows] fp32 chunk-major (2 KB),
//              B [4 chunks][128 rows] bf16 chunk-major (8 KB)
//   chunk-major layout (free via DMA source-address permutation) makes all
//   fragment ds_read_b128 stride 16 B across rows -> 2-way banks = free.
//   K-step 32 (one MFMA k-chunk); 10 DMA instrs/block/step (w0/w1: 1A+2B,
//   w2/w3: 2B); rowsum fused into the A-fragment path; direct 64B-segment
//   epilogue stores (R4-verified clean WRITE_SIZE).
// ---------------------------------------------------------------------------
__global__ __launch_bounds__(256) void gcn_kernel(const float* __restrict__ adj,
                                                  const unsigned short* __restrict__ Yt,
                                                  const float* __restrict__ bias,
                                                  float* __restrict__ out) {
    __shared__ char smem[10240];          // A: [0,2048)  B: [2048,10240)

    const int tid  = threadIdx.x;
    const int lane = tid & 63;
    const int w    = tid >> 6;
    const int bid  = blockIdx.x;
    const int b    = bid >> 6;
    const int n0   = (bid & 63) * 16;

    const int lcol = lane & 15;           // fragment row selector / C col
    const int q    = lane >> 4;           // k-octet selector
    const int wn   = w * 32;              // o-offset of this wave (16n x 32o)

    // --- DMA sources (chunk-major LDS via source permutation) ---
    // A instr i (i=w, valid w<2): LDS chunk L=i*64+lane -> c=L>>4 (=i*4+q'),
    //   row=L&15; src = adj row (n0+row), fp32 k-offset c*4.
    const float* aSrc = adj
        + ((size_t)(b * NN + n0 + (lane & 15))) * NN
        + ((w & 1) * 4 + (lane >> 4)) * 4;
    char* aDst = smem + (w & 1) * 1024;

    // B instrs i=w and i=w+4: L=i*64+lane -> c=L>>7=i>>1 (+2 for i+4),
    //   row=L&127=(i&1)*64+lane (same row for both!).
    const unsigned short* bSrc = Yt
        + ((size_t)(b * FOUT + (w & 1) * 64 + lane)) * NN
        + (w >> 1) * 8;
    char* bDst1 = smem + 2048 + w * 1024;
    char* bDst2 = smem + 2048 + (w + 4) * 1024;

    const float bcol0 = bias[wn + lcol];
    const float bcol1 = bias[wn + 16 + lcol];

    f32x4 acc0 = {}, acc1 = {};
    float rsum = 0.f;

    // fragment LDS addresses (loop-invariant)
    const char* aF0 = smem + q * 512 + lcol * 16;          // chunk 2q, row lcol
    const char* aF1 = aF0 + 256;                           // chunk 2q+1
    const char* bF0 = smem + 2048 + q * 2048 + (wn + lcol) * 16;
    const char* bF1 = bF0 + 256;                           // ni=1 (+16 rows)

    for (int s = 0; s < 32; ++s) {
        if (w < 2) load_lds16(aSrc, aDst);
        load_lds16(bSrc,      bDst1);
        load_lds16(bSrc + 16, bDst2);
        __syncthreads();                  // vmcnt drain -> LDS data visible

        const float4 fa0 = *(const float4*)aF0;
        const float4 fa1 = *(const float4*)aF1;
        rsum += ((fa0.x + fa0.y) + (fa0.z + fa0.w))
              + ((fa1.x + fa1.y) + (fa1.z + fa1.w));
        uint4 pk;
        pk.x = pack2(fa0.x, fa0.y); pk.y = pack2(fa0.z, fa0.w);
        pk.z = pack2(fa1.x, fa1.y); pk.w = pack2(fa1.z, fa1.w);
        const bf16x8 af  = *(const bf16x8*)&pk;
        const bf16x8 bf0 = *(const bf16x8*)bF0;
        const bf16x8 bf1 = *(const bf16x8*)bF1;
        acc0 = __builtin_amdgcn_mfma_f32_16x16x32_bf16(af, bf0, acc0, 0, 0, 0);
        acc1 = __builtin_amdgcn_mfma_f32_16x16x32_bf16(af, bf1, acc1, 0, 0, 0);
        __syncthreads();                  // reads done before next overwrite

        aSrc += 32; bSrc += 32;
    }

    // rowsum: lanes with equal lcol hold disjoint k-octets of row (n0+lcol)
    rsum += __shfl_xor(rsum, 16);
    rsum += __shfl_xor(rsum, 32);

    // C/D frag: col = lane&15 (o), row = q*4 + reg (n)
    float sc[4];
    #pragma unroll
    for (int r = 0; r < 4; ++r) sc[r] = 1.0f / __shfl(rsum, q * 4 + r);

    float* outB = out + ((size_t)(b * NN + n0)) * FOUT;
    #pragma unroll
    for (int r = 0; r < 4; ++r) {
        const int row = q * 4 + r;
        float v0 = acc0[r] * sc[r] + bcol0;
        float v1 = acc1[r] * sc[r] + bcol1;
        v0 = (v0 >= 0.f) ? v0 : 0.01f * v0;
        v1 = (v1 >= 0.f) ? v1 : 0.01f * v1;
        outB[(size_t)row * FOUT + wn + lcol]      = v0;
        outB[(size_t)row * FOUT + wn + 16 + lcol] = v1;
    }
}

extern "C" void kernel_launch(void* const* d_in, const int* in_sizes, int n_in,
                              void* d_out, int out_size, void* d_ws, size_t ws_size,
                              hipStream_t stream) {
    const float* node = (const float*)d_in[0];   // [32,1024,128]
    const float* adj  = (const float*)d_in[1];   // [32,1024,1024]
    const float* W    = (const float*)d_in[2];   // [128,128]
    const float* bias = (const float*)d_in[3];   // [128]
    float* out = (float*)d_out;                  // [32,1024,128] fp32
    unsigned short* Yt = (unsigned short*)d_ws;  // [32,128,1024] bf16 = 8 MiB

    hipLaunchKernelGGL(y_kernel,   dim3(512),  dim3(256), 0, stream, node, W, Yt);
    hipLaunchKernelGGL(gcn_kernel, dim3(2048), dim3(256), 0, stream, adj, Yt, bias, out);
}

// Round 6
// 230.616 us; speedup vs baseline: 1.3503x; 1.3503x over previous
//
#include <hip/hip_runtime.h>
#include <cstdint>
#include <cstddef>

#define BB   32
#define NN   1024
#define FIN  128
#define FOUT 128

typedef __attribute__((ext_vector_type(8))) short bf16x8;
typedef __attribute__((ext_vector_type(4))) float f32x4;

__device__ __forceinline__ unsigned int f2bf(float f) {
    union { float f; unsigned int u; } v; v.f = f;
    unsigned int u = v.u;
    return (u + 0x7FFFu + ((u >> 16) & 1u)) >> 16;   // RNE fp32 -> bf16
}
__device__ __forceinline__ unsigned int pack2(float a, float b) {
    return f2bf(a) | (f2bf(b) << 16);
}

// async global -> LDS DMA, 16 B/lane; dst is wave-uniform base, HW scatters
// lane i to dst + i*16 (m97/m104 semantics)
__device__ __forceinline__ void load_lds16(const void* g, void* l) {
    __builtin_amdgcn_global_load_lds(
        (const __attribute__((address_space(1))) unsigned int*)g,
        (__attribute__((address_space(3))) unsigned int*)l, 16, 0, 0);
}

// ---------------------------------------------------------------------------
// Kernel 1: Yt[b][o][m] = sum_f node[b][m][f] * W[o][f]  (bf16, [B][FOUT][NN])
// grid 512 = 32 b x 16 m-tiles(64); block 256. LDS-staged. (control, ~10 us)
// ---------------------------------------------------------------------------
__global__ __launch_bounds__(256) void y_kernel(const float* __restrict__ node,
                                                const float* __restrict__ W,
                                                unsigned short* __restrict__ Yt) {
    __shared__ unsigned short Wlds[128 * 136];
    __shared__ unsigned short Nlds[64 * 136];

    const int tid = threadIdx.x;
    const int bid = blockIdx.x;
    const int b   = bid >> 4;
    const int m0  = (bid & 15) * 64;

    #pragma unroll
    for (int i = 0; i < 16; ++i) {
        const int idx = i * 256 + tid;
        const int row = idx >> 5;
        const int c   = (idx & 31) * 4;
        float4 v = ((const float4*)W)[idx];
        uint2 p; p.x = pack2(v.x, v.y); p.y = pack2(v.z, v.w);
        *(uint2*)&Wlds[row * 136 + c] = p;
    }
    {
        const float* base = node + ((size_t)b * NN + m0) * FIN;
        #pragma unroll
        for (int i = 0; i < 8; ++i) {
            const int idx = i * 256 + tid;
            const int row = idx >> 5;
            const int c   = (idx & 31) * 4;
            float4 v = *(const float4*)(base + row * FIN + c);
            uint2 p; p.x = pack2(v.x, v.y); p.y = pack2(v.z, v.w);
            *(uint2*)&Nlds[row * 136 + c] = p;
        }
    }
    __syncthreads();

    const int w = tid >> 6, lane = tid & 63;
    const int wo = w * 32;
    const int lcol = lane & 15, lk = (lane >> 4) * 8;

    f32x4 acc[2][4] = {};
    #pragma unroll
    for (int kc = 0; kc < 4; ++kc) {
        const int kof = kc * 32 + lk;
        bf16x8 a[2], bb[4];
        #pragma unroll
        for (int mi = 0; mi < 2; ++mi)
            a[mi] = *(const bf16x8*)&Wlds[(wo + mi*16 + lcol) * 136 + kof];
        #pragma unroll
        for (int ni = 0; ni < 4; ++ni)
            bb[ni] = *(const bf16x8*)&Nlds[(ni*16 + lcol) * 136 + kof];
        #pragma unroll
        for (int mi = 0; mi < 2; ++mi)
            #pragma unroll
            for (int ni = 0; ni < 4; ++ni)
                acc[mi][ni] = __builtin_amdgcn_mfma_f32_16x16x32_bf16(
                    a[mi], bb[ni], acc[mi][ni], 0, 0, 0);
    }
    __syncthreads();

    unsigned short* Ylds = Wlds;
    const int rq = (lane >> 4) * 4;
    #pragma unroll
    for (int mi = 0; mi < 2; ++mi)
        #pragma unroll
        for (int ni = 0; ni < 4; ++ni)
            #pragma unroll
            for (int r = 0; r < 4; ++r) {
                const int o = wo + mi * 16 + rq + r;
                const int m = ni * 16 + lcol;
                Ylds[o * 72 + m] = (unsigned short)f2bf(acc[mi][ni][r]);
            }
    __syncthreads();

    {
        const int oq = tid >> 3, c = (tid & 7) * 8;
        #pragma unroll
        for (int j = 0; j < 4; ++j) {
            const int o = oq + 32 * j;
            uint4 v = *(const uint4*)&Ylds[o * 72 + c];
            *(uint4*)(Yt + ((size_t)b * FOUT + o) * NN + m0 + c) = v;
        }
    }
}

// ---------------------------------------------------------------------------
// Kernel 2: out = leaky( (adj @ Yt^T) / rowsum(adj) + bias )
// R3's DMA structure (line-sized source segments: A 4rowsx256B, B 8rowsx128B,
// XOR chunk swizzle -> 2-way banks) + DOUBLE-BUFFERED LDS with inline-asm
// fine-grained s_waitcnt vmcnt(6) + raw s_barrier (AITER-style, never drains
// to 0 until the tail). 6 DMA instrs/wave/step; one step of prefetch depth.
// grid 1024 = 32 b x 32 n-tiles(32); block 256 (2x2 waves over 32n x 128o);
// LDS 48 KB -> 3 blocks/CU. Rowsum fused in A-fragment path; direct stores.
// ---------------------------------------------------------------------------
__global__ __launch_bounds__(256) void gcn_kernel(const float* __restrict__ adj,
                                                  const unsigned short* __restrict__ Yt,
                                                  const float* __restrict__ bias,
                                                  float* __restrict__ out) {
    __shared__ char smem[2 * 24576];      // per buffer: A [0,8192) B [8192,24576)

    const int tid  = threadIdx.x;
    const int lane = tid & 63;
    const int w    = tid >> 6;
    const int bid  = blockIdx.x;
    const int b    = bid >> 5;
    const int n0   = (bid & 31) * 32;

    const int lcol = lane & 15, q = lane >> 4;
    const int wm = (w & 1) * 16, wn = (w >> 1) * 64;
    const int key = lcol & 7;

    // ---- DMA sources (XOR chunk swizzle inside each row; segments >= 128B) ----
    // A: 32 rows x 64 fp32 = 512 chunks(16B), 8 instrs (2/wave), 4 rows x 256 B each
    const float* aSrc[2]; int aOff[2];
    #pragma unroll
    for (int j = 0; j < 2; ++j) {
        const int s = (w * 2 + j) * 64 + lane;
        const int r = s >> 4, c = s & 15;
        const int g = c ^ (r & 7);
        aSrc[j] = adj + ((size_t)(b * NN + n0 + r)) * NN + g * 4;
        aOff[j] = (w * 2 + j) * 1024;
    }
    // B: 128 rows x 64 bf16 = 1024 chunks, 16 instrs (4/wave), 8 rows x 128 B each
    const unsigned short* bSrcp[4]; int bOff[4];
    #pragma unroll
    for (int j = 0; j < 4; ++j) {
        const int s = (w * 4 + j) * 64 + lane;
        const int o = s >> 3, c = s & 7;
        const int g = c ^ (o & 7);
        bSrcp[j] = Yt + ((size_t)(b * FOUT + o)) * NN + g * 8;
        bOff[j] = 8192 + (w * 4 + j) * 1024;
    }

    // fragment LDS byte offsets within one buffer (swizzle folded in)
    int offA[2][2], offB[2][4];
    #pragma unroll
    for (int kc = 0; kc < 2; ++kc) {
        const int gA = kc * 8 + q * 2;
        const int R  = wm + lcol;
        offA[kc][0] = R * 256 + (( gA     ) ^ key) * 16;
        offA[kc][1] = R * 256 + (( gA + 1 ) ^ key) * 16;
        #pragma unroll
        for (int ni = 0; ni < 4; ++ni) {
            const int Rb = wn + ni * 16 + lcol;
            const int gB = kc * 4 + q;
            offB[kc][ni] = 8192 + Rb * 128 + (gB ^ key) * 16;
        }
    }

    f32x4 acc[4] = {};
    float rsum = 0.f;

    auto compute = [&](const char* cb) {
        #pragma unroll
        for (int kc = 0; kc < 2; ++kc) {
            const float4 f0 = *(const float4*)(cb + offA[kc][0]);
            const float4 f1 = *(const float4*)(cb + offA[kc][1]);
            rsum += ((f0.x + f0.y) + (f0.z + f0.w))
                  + ((f1.x + f1.y) + (f1.z + f1.w));
            uint4 pk;
            pk.x = pack2(f0.x, f0.y); pk.y = pack2(f0.z, f0.w);
            pk.z = pack2(f1.x, f1.y); pk.w = pack2(f1.z, f1.w);
            const bf16x8 af = *(const bf16x8*)&pk;
            #pragma unroll
            for (int ni = 0; ni < 4; ++ni) {
                const bf16x8 bb = *(const bf16x8*)(cb + offB[kc][ni]);
                acc[ni] = __builtin_amdgcn_mfma_f32_16x16x32_bf16(af, bb, acc[ni], 0, 0, 0);
            }
        }
    };

    // prologue: step 0 -> buf 0
    #pragma unroll
    for (int j = 0; j < 2; ++j) load_lds16(aSrc[j], smem + aOff[j]);
    #pragma unroll
    for (int j = 0; j < 4; ++j) load_lds16(bSrcp[j], smem + bOff[j]);

    for (int s = 0; s < 15; ++s) {
        char*       nb = smem + ((s + 1) & 1) * 24576;
        const char* cb = smem + ( s      & 1) * 24576;
        // issue step s+1 into the other buffer (safe: last reader of that
        // buffer finished before the previous iteration's tail barrier)
        #pragma unroll
        for (int j = 0; j < 2; ++j) load_lds16(aSrc[j] + (s + 1) * 64, nb + aOff[j]);
        #pragma unroll
        for (int j = 0; j < 4; ++j) load_lds16(bSrcp[j] + (s + 1) * 64, nb + bOff[j]);

        // wait only for step s's 6 DMAs (s+1's 6 remain in flight), then align
        asm volatile("s_waitcnt vmcnt(6)\n\ts_barrier" ::: "memory");
        compute(cb);
        // all lanes' LDS reads complete before anyone overwrites this buffer
        asm volatile("s_waitcnt lgkmcnt(0)\n\ts_barrier" ::: "memory");
    }

    // tail: step 15 in buf 1
    asm volatile("s_waitcnt vmcnt(0)\n\ts_barrier" ::: "memory");
    compute(smem + 24576);

    // rowsum: lanes with equal lcol hold disjoint k-octets of row (n0+wm+lcol)
    rsum += __shfl_xor(rsum, 16);
    rsum += __shfl_xor(rsum, 32);

    // C/D frag: col = lane&15 (o), row = q*4 + reg (n)
    float sc[4];
    #pragma unroll
    for (int r = 0; r < 4; ++r) sc[r] = 1.0f / __shfl(rsum, q * 4 + r);
    float bcol[4];
    #pragma unroll
    for (int ni = 0; ni < 4; ++ni) bcol[ni] = bias[wn + ni * 16 + lcol];

    float* outB = out + ((size_t)(b * NN + n0 + wm)) * FOUT;
    #pragma unroll
    for (int ni = 0; ni < 4; ++ni) {
        #pragma unroll
        for (int r = 0; r < 4; ++r) {
            float v = acc[ni][r] * sc[r] + bcol[ni];
            v = (v >= 0.f) ? v : 0.01f * v;
            outB[(size_t)(q * 4 + r) * FOUT + wn + ni * 16 + lcol] = v;
        }
    }
}

extern "C" void kernel_launch(void* const* d_in, const int* in_sizes, int n_in,
                              void* d_out, int out_size, void* d_ws, size_t ws_size,
                              hipStream_t stream) {
    const float* node = (const float*)d_in[0];   // [32,1024,128]
    const float* adj  = (const float*)d_in[1];   // [32,1024,1024]
    const float* W    = (const float*)d_in[2];   // [128,128]
    const float* bias = (const float*)d_in[3];   // [128]
    float* out = (float*)d_out;                  // [32,1024,128] fp32
    unsigned short* Yt = (unsigned short*)d_ws;  // [32,128,1024] bf16 = 8 MiB

    hipLaunchKernelGGL(y_kernel,   dim3(512),  dim3(256), 0, stream, node, W, Yt);
    hipLaunchKernelGGL(gcn_kernel, dim3(1024), dim3(256), 0, stream, adj, Yt, bias, out);
}